// Round 2
// baseline (813.480 us; speedup 1.0000x reference)
//
#include <hip/hip_runtime.h>
#include <hip/hip_bf16.h>

typedef unsigned short u16;
typedef __attribute__((ext_vector_type(8))) short short8;
typedef __attribute__((ext_vector_type(4))) float f32x4;

#define BATCH 32
#define CIN   96
#define LSEQ  4096
#define DIN   256
#define NST   16
#define MROWS (BATCH * LSEQ)   // 131072
#define SCHUNKS 32
#define LCHUNK  128            // LSEQ / SCHUNKS

__device__ __forceinline__ float b2f(u16 u) {
    union { unsigned int i; float f; } v; v.i = ((unsigned int)u) << 16; return v.f;
}
__device__ __forceinline__ u16 f2b(float f) {
    union { float f; unsigned int i; } v; v.f = f;
    unsigned int i = v.i;
    unsigned int lsb = (i >> 16) & 1u;
    return (u16)((i + 0x7fffu + lsb) >> 16);
}

// ---------------------------------------------------------------------------
// K0: fp32 -> bf16 conversion for MFMA weight operands
// ---------------------------------------------------------------------------
__global__ __launch_bounds__(256) void k0_cvt(
    const float* __restrict__ src, u16* __restrict__ dst, int n)
{
    int i = blockIdx.x * 256 + threadIdx.x;
    if (i < n) dst[i] = f2b(src[i]);
}

// ---------------------------------------------------------------------------
// K1: xz[m, 0:512] = h_in[m, 0:96] @ in_proj_w^T + b ; h_in[b*L+l, c] = x[b,c,l]
// Block: 64 rows (l) x 256 cols (n). A staged transposed via LDS (x is (b,c,L) fp32).
// ---------------------------------------------------------------------------
__global__ __launch_bounds__(256) void k1_inproj(
    const float* __restrict__ x, const u16* __restrict__ wp,
    const float* __restrict__ bias, u16* __restrict__ xz)
{
    __shared__ u16 AtT[96 * 65];   // [c][l] pitch 65 (odd -> conflict-light)
    int m0 = blockIdx.x * 64;
    int b  = m0 >> 12;
    int l0 = m0 & 4095;
    int n0 = blockIdx.y * 256;
    int t  = threadIdx.x;
    {
        int i = t & 63, c0 = t >> 6;
        for (int c = c0; c < 96; c += 4)
            AtT[c * 65 + i] = f2b(x[((size_t)(b * 96 + c)) * 4096 + l0 + i]);
    }
    __syncthreads();
    int lane = t & 63, wid = t >> 6, q = lane >> 4, ml = lane & 15;
    f32x4 acc[16];
    #pragma unroll
    for (int f = 0; f < 16; f++)
        #pragma unroll
        for (int r = 0; r < 4; r++) acc[f][r] = 0.f;
    int arow = wid * 16 + ml;
    for (int k0 = 0; k0 < 96; k0 += 32) {
        union { short8 v; u16 u[8]; } a;
        int kb = k0 + q * 8;
        #pragma unroll
        for (int j = 0; j < 8; j++) a.u[j] = AtT[(kb + j) * 65 + arow];
        #pragma unroll
        for (int f = 0; f < 16; f++) {
            int n = n0 + f * 16 + ml;
            short8 bf = *(const short8*)&wp[(size_t)n * 96 + kb];
            acc[f] = __builtin_amdgcn_mfma_f32_16x16x32_bf16(a.v, bf, acc[f], 0, 0, 0);
        }
    }
    #pragma unroll
    for (int f = 0; f < 16; f++) {
        int n = n0 + f * 16 + ml;
        float bs = bias[n];
        #pragma unroll
        for (int r = 0; r < 4; r++) {
            int m = m0 + wid * 16 + q * 4 + r;
            xz[(size_t)m * 512 + n] = f2b(acc[f][r] + bs);
        }
    }
}

// ---------------------------------------------------------------------------
// K2: u[b,l,d] = silu( sum_k conv_w[d,k] * x_res[b, l-3+k, d] + conv_b[d] )
// x_res = xz[:, 0:256]. Thread = d, rolling window over l-chunk of 64.
// ---------------------------------------------------------------------------
__global__ __launch_bounds__(256) void k2_conv(
    const u16* __restrict__ xz, const float* __restrict__ cw,
    const float* __restrict__ cb, u16* __restrict__ u)
{
    int d  = threadIdx.x;
    int b  = blockIdx.y;
    int l0 = blockIdx.x * 64;
    float w0 = cw[d * 4 + 0], w1 = cw[d * 4 + 1];
    float w2 = cw[d * 4 + 2], w3 = cw[d * 4 + 3];
    float bias = cb[d];
    size_t rowbase = ((size_t)b * 4096) * 512 + d;
    size_t ubase   = ((size_t)b * 4096) * 256 + d;
    float x0 = (l0 >= 3) ? b2f(xz[rowbase + (size_t)(l0 - 3) * 512]) : 0.f;
    float x1 = (l0 >= 2) ? b2f(xz[rowbase + (size_t)(l0 - 2) * 512]) : 0.f;
    float x2 = (l0 >= 1) ? b2f(xz[rowbase + (size_t)(l0 - 1) * 512]) : 0.f;
    for (int l = l0; l < l0 + 64; l++) {
        float x3 = b2f(xz[rowbase + (size_t)l * 512]);
        float s  = w0 * x0 + w1 * x1 + w2 * x2 + w3 * x3 + bias;
        float sig = 1.f / (1.f + __expf(-s));
        u[ubase + (size_t)l * 256] = f2b(s * sig);
        x0 = x1; x1 = x2; x2 = x3;
    }
}

// ---------------------------------------------------------------------------
// K3: dtbc[64x48] = u_tile @ x_proj_w^T  (MFMA, A direct from global)
//     B,C = dtbc[:,16:32], [:,32:48] (fp32 out); dt = softplus(dtbc[:,0:16] @ dt_proj_w^T + b)
// ---------------------------------------------------------------------------
__global__ __launch_bounds__(256) void k3_xproj(
    const u16* __restrict__ u, const u16* __restrict__ xw,
    const float* __restrict__ dw, const float* __restrict__ db,
    u16* __restrict__ dt, float* __restrict__ Bb, float* __restrict__ Cb)
{
    __shared__ float dtbc[64][49];
    int m0 = blockIdx.x * 64;
    int t  = threadIdx.x;
    int lane = t & 63, wid = t >> 6, q = lane >> 4, ml = lane & 15;
    f32x4 acc[3];
    #pragma unroll
    for (int f = 0; f < 3; f++)
        #pragma unroll
        for (int r = 0; r < 4; r++) acc[f][r] = 0.f;
    int arow = wid * 16 + ml;
    const u16* ap = &u[(size_t)(m0 + arow) * 256];
    #pragma unroll
    for (int k0 = 0; k0 < 256; k0 += 32) {
        short8 a = *(const short8*)&ap[k0 + q * 8];
        #pragma unroll
        for (int f = 0; f < 3; f++) {
            short8 bf = *(const short8*)&xw[(size_t)(f * 16 + ml) * 256 + k0 + q * 8];
            acc[f] = __builtin_amdgcn_mfma_f32_16x16x32_bf16(a, bf, acc[f], 0, 0, 0);
        }
    }
    #pragma unroll
    for (int f = 0; f < 3; f++)
        #pragma unroll
        for (int r = 0; r < 4; r++)
            dtbc[wid * 16 + q * 4 + r][f * 16 + ml] = acc[f][r];
    __syncthreads();
    {   // B, C writes
        int row = t >> 5, cc = t & 31;
        for (int p = 0; p < 8; p++) {
            int rr = row + p * 8;
            float v = dtbc[rr][16 + cc];
            size_t idx = (size_t)(m0 + rr) * 16 + (cc & 15);
            if (cc < 16) Bb[idx] = v; else Cb[idx] = v;
        }
    }
    {   // dt: thread = d
        int d = t;
        float wr[16];
        #pragma unroll
        for (int j = 0; j < 16; j++) wr[j] = dw[d * 16 + j];
        float bias = db[d];
        for (int r = 0; r < 64; r++) {
            float s = bias;
            #pragma unroll
            for (int j = 0; j < 16; j++) s += dtbc[r][j] * wr[j];
            float sp = (s > 20.f) ? s : __logf(1.f + __expf(s));
            dt[(size_t)(m0 + r) * 256 + d] = f2b(sp);
        }
    }
}

// ---------------------------------------------------------------------------
// K4: scan pass A — per chunk: local final state (h from 0) + decay product
// ---------------------------------------------------------------------------
__global__ __launch_bounds__(256) void k4_scanA(
    const u16* __restrict__ dt, const u16* __restrict__ u,
    const float* __restrict__ Bb, const float* __restrict__ alog,
    float* __restrict__ hloc, float* __restrict__ aprod)
{
    __shared__ float Bs[LCHUNK * 16];
    int s = blockIdx.x, b = blockIdx.y;
    int l0 = s * LCHUNK;
    int d = threadIdx.x;
    float A[16];
    #pragma unroll
    for (int n = 0; n < 16; n++) A[n] = -__expf(alog[d * 16 + n]);
    const float* bsrc = &Bb[((size_t)b * 4096 + l0) * 16];
    for (int jj = threadIdx.x; jj < LCHUNK * 16; jj += 256) Bs[jj] = bsrc[jj];
    __syncthreads();
    float h[16], apd[16];
    #pragma unroll
    for (int n = 0; n < 16; n++) { h[n] = 0.f; apd[n] = 1.f; }
    size_t base = ((size_t)b * 4096 + l0) * 256 + d;
    for (int i = 0; i < LCHUNK; i++) {
        float dtv = b2f(dt[base + (size_t)i * 256]);
        float uv  = b2f(u [base + (size_t)i * 256]);
        float du  = dtv * uv;
        #pragma unroll
        for (int n = 0; n < 16; n++) {
            float dA = __expf(dtv * A[n]);
            apd[n] *= dA;
            h[n] = dA * h[n] + du * Bs[i * 16 + n];
        }
    }
    size_t o = (((size_t)s * 32 + b) * 256 + d) * 16;
    #pragma unroll
    for (int n = 0; n < 16; n++) { hloc[o + n] = h[n]; aprod[o + n] = apd[n]; }
}

// ---------------------------------------------------------------------------
// K5: scan pass B — sequential carry combine across 32 chunks per (b,d,n)
// ---------------------------------------------------------------------------
__global__ __launch_bounds__(256) void k5_scanB(
    const float* __restrict__ hloc, const float* __restrict__ aprod,
    float* __restrict__ hin)
{
    int t = blockIdx.x * 256 + threadIdx.x;   // 131072 = (b, d, n)
    int b = t >> 12;
    int rem = t & 4095;
    float h = 0.f;
    for (int s = 0; s < SCHUNKS; s++) {
        size_t o = ((size_t)(s * 32 + b)) * 4096 + rem;
        float hl = hloc[o], ap = aprod[o];
        hin[o] = h;
        h = ap * h + hl;
    }
}

// ---------------------------------------------------------------------------
// K6: scan pass C — true scan with carry-in; fuse y+u*D, *silu(z), +x_res.
// ut is u on input, overwritten in place with the pre-LN1 tensor t.
// ---------------------------------------------------------------------------
__global__ __launch_bounds__(256) void k6_scanC(
    const u16* __restrict__ dt, u16* ut,
    const float* __restrict__ Bb, const float* __restrict__ Cb,
    const float* __restrict__ alog, const float* __restrict__ hin,
    const u16* __restrict__ xz, const float* __restrict__ Dp)
{
    __shared__ float Bs[LCHUNK * 16];
    __shared__ float Cs[LCHUNK * 16];
    int s = blockIdx.x, b = blockIdx.y;
    int l0 = s * LCHUNK;
    int d = threadIdx.x;
    float A[16];
    #pragma unroll
    for (int n = 0; n < 16; n++) A[n] = -__expf(alog[d * 16 + n]);
    {
        const float* bsrc = &Bb[((size_t)b * 4096 + l0) * 16];
        const float* csrc = &Cb[((size_t)b * 4096 + l0) * 16];
        for (int jj = threadIdx.x; jj < LCHUNK * 16; jj += 256) {
            Bs[jj] = bsrc[jj]; Cs[jj] = csrc[jj];
        }
    }
    __syncthreads();
    float h[16];
    {
        size_t o = (((size_t)s * 32 + b) * 256 + d) * 16;
        #pragma unroll
        for (int n = 0; n < 16; n++) h[n] = hin[o + n];
    }
    float Dv = Dp[d];
    size_t base  = ((size_t)b * 4096 + l0) * 256 + d;
    size_t zbase = ((size_t)b * 4096 + l0) * 512 + d;
    for (int i = 0; i < LCHUNK; i++) {
        float dtv = b2f(dt[base + (size_t)i * 256]);
        float uv  = b2f(ut[base + (size_t)i * 256]);
        float du  = dtv * uv;
        float y = 0.f;
        #pragma unroll
        for (int n = 0; n < 16; n++) {
            float dA = __expf(dtv * A[n]);
            h[n] = dA * h[n] + du * Bs[i * 16 + n];
            y += h[n] * Cs[i * 16 + n];
        }
        y += uv * Dv;
        float zv = b2f(xz[zbase + (size_t)i * 512 + 256]);
        float xr = b2f(xz[zbase + (size_t)i * 512]);
        float sig = 1.f / (1.f + __expf(-zv));
        y *= zv * sig;
        ut[base + (size_t)i * 256] = f2b(y + xr);
    }
}

// ---------------------------------------------------------------------------
// K8: y1 = LN1(t); y_proj = y1 @ out_proj_w^T + ob; out = LN2(y1 + y_proj)
// Block: 64 rows, full N=256 so both LNs are in-block. Output fp32.
// ---------------------------------------------------------------------------
__global__ __launch_bounds__(256) void k8_final(
    const u16* __restrict__ tb, const u16* __restrict__ ow,
    const float* __restrict__ ob, const float* __restrict__ g1,
    const float* __restrict__ bb1, const float* __restrict__ g2,
    const float* __restrict__ bb2, float* __restrict__ out)
{
    __shared__ u16 Yt[64 * 272];
    int m0 = blockIdx.x * 64;
    int t  = threadIdx.x;
    {   // load + LN1 (4 threads per row, shuffle-combine partials)
        int r = t >> 2, ccol = (t & 3) * 64;
        const u16* src = &tb[(size_t)(m0 + r) * 256 + ccol];
        u16* dst = &Yt[r * 272 + ccol];
        float sum = 0.f, sq = 0.f;
        #pragma unroll
        for (int jj = 0; jj < 64; jj += 8) {
            short8 v = *(const short8*)&src[jj];
            *(short8*)&dst[jj] = v;
            #pragma unroll
            for (int e = 0; e < 8; e++) {
                float f = b2f((u16)v[e]); sum += f; sq += f * f;
            }
        }
        sum += __shfl_xor(sum, 1); sq += __shfl_xor(sq, 1);
        sum += __shfl_xor(sum, 2); sq += __shfl_xor(sq, 2);
        float mean = sum * (1.f / 256.f);
        float var  = sq * (1.f / 256.f) - mean * mean;
        float rstd = rsqrtf(var + 1e-5f);
        for (int jj = 0; jj < 64; jj++) {
            int c = ccol + jj;
            float f = b2f(dst[jj]);
            dst[jj] = f2b((f - mean) * rstd * g1[c] + bb1[c]);
        }
    }
    __syncthreads();
    int lane = t & 63, wid = t >> 6, q = lane >> 4, ml = lane & 15;
    f32x4 acc[16];
    #pragma unroll
    for (int f = 0; f < 16; f++)
        #pragma unroll
        for (int r = 0; r < 4; r++) acc[f][r] = 0.f;
    int arow = wid * 16 + ml;
    #pragma unroll
    for (int k0 = 0; k0 < 256; k0 += 32) {
        short8 a = *(const short8*)&Yt[arow * 272 + k0 + q * 8];
        #pragma unroll
        for (int f = 0; f < 16; f++) {
            short8 bf = *(const short8*)&ow[(size_t)(f * 16 + ml) * 256 + k0 + q * 8];
            acc[f] = __builtin_amdgcn_mfma_f32_16x16x32_bf16(a, bf, acc[f], 0, 0, 0);
        }
    }
    // residual + LN2 (reduce over 16 ml-lanes per row)
    float ps[4] = {0, 0, 0, 0}, psq[4] = {0, 0, 0, 0};
    #pragma unroll
    for (int f = 0; f < 16; f++) {
        int col = f * 16 + ml;
        float obv = ob[col];
        #pragma unroll
        for (int r = 0; r < 4; r++) {
            int row = wid * 16 + q * 4 + r;
            float v = acc[f][r] + obv + b2f(Yt[row * 272 + col]);
            acc[f][r] = v;
            ps[r] += v; psq[r] += v * v;
        }
    }
    #pragma unroll
    for (int msk = 1; msk < 16; msk <<= 1) {
        #pragma unroll
        for (int r = 0; r < 4; r++) {
            ps[r]  += __shfl_xor(ps[r],  msk);
            psq[r] += __shfl_xor(psq[r], msk);
        }
    }
    #pragma unroll
    for (int f = 0; f < 16; f++) {
        int col = f * 16 + ml;
        float g2v = g2[col], b2v = bb2[col];
        #pragma unroll
        for (int r = 0; r < 4; r++) {
            int row = wid * 16 + q * 4 + r;
            float mean = ps[r] * (1.f / 256.f);
            float var  = psq[r] * (1.f / 256.f) - mean * mean;
            float rstd = rsqrtf(var + 1e-5f);
            out[(size_t)(m0 + row) * 256 + col] = (acc[f][r] - mean) * rstd * g2v + b2v;
        }
    }
}

extern "C" void kernel_launch(void* const* d_in, const int* in_sizes, int n_in,
                              void* d_out, int out_size, void* d_ws, size_t ws_size,
                              hipStream_t stream)
{
    const float* x    = (const float*)d_in[0];
    const float* ipw  = (const float*)d_in[1];
    const float* ipb  = (const float*)d_in[2];
    const float* cw   = (const float*)d_in[3];
    const float* cb   = (const float*)d_in[4];
    const float* xpw  = (const float*)d_in[5];
    const float* dpw  = (const float*)d_in[6];
    const float* dpb  = (const float*)d_in[7];
    const float* opw  = (const float*)d_in[8];
    const float* opb  = (const float*)d_in[9];
    const float* alog = (const float*)d_in[10];
    const float* Dp   = (const float*)d_in[11];
    const float* g1   = (const float*)d_in[12];
    const float* b1   = (const float*)d_in[13];
    const float* g2   = (const float*)d_in[14];
    const float* b2   = (const float*)d_in[15];

    char* ws = (char*)d_ws;
    const size_t M = (size_t)MROWS;
    u16*  xz  = (u16*)ws;                                   // M*512*2 = 134217728
    u16*  u   = (u16*)(ws + 134217728);                     // M*256*2 = 67108864 (reused as t)
    u16*  dt  = (u16*)(ws + 134217728 + 67108864);          // 67108864
    float* Bb = (float*)(ws + 134217728 + 2 * 67108864);    // M*16*4 = 8388608
    float* Cb = Bb + M * 16;                                // 8388608
    float* hloc  = Cb + M * 16;                             // 32*32*256*16*4 = 16777216
    float* aprod = hloc + 4194304;
    float* hin   = aprod + 4194304;                         // end: 335544320
    u16* ipw_b = (u16*)(ws + 335544320);                    // 512*96   = 49152 el
    u16* xpw_b = ipw_b + 49152;                             // 48*256   = 12288 el
    u16* opw_b = xpw_b + 12288;                             // 256*256  = 65536 el
    float* outp = (float*)d_out;

    k0_cvt<<<192, 256, 0, stream>>>(ipw, ipw_b, 49152);
    k0_cvt<<<48,  256, 0, stream>>>(xpw, xpw_b, 12288);
    k0_cvt<<<256, 256, 0, stream>>>(opw, opw_b, 65536);
    k1_inproj<<<dim3(2048, 2), 256, 0, stream>>>(x, ipw_b, ipb, xz);
    k2_conv  <<<dim3(64, 32),  256, 0, stream>>>(xz, cw, cb, u);
    k3_xproj <<<2048,          256, 0, stream>>>(u, xpw_b, dpw, dpb, dt, Bb, Cb);
    k4_scanA <<<dim3(32, 32),  256, 0, stream>>>(dt, u, Bb, alog, hloc, aprod);
    k5_scanB <<<512,           256, 0, stream>>>(hloc, aprod, hin);
    k6_scanC <<<dim3(32, 32),  256, 0, stream>>>(dt, u, Bb, Cb, alog, hin, xz, Dp);
    k8_final <<<2048,          256, 0, stream>>>(u, opw_b, opb, g1, b1, g2, b2, outp);
}

// Round 3
// 732.936 us; speedup vs baseline: 1.1099x; 1.1099x over previous
//
#include <hip/hip_runtime.h>
#include <hip/hip_bf16.h>

typedef unsigned short u16;
typedef __attribute__((ext_vector_type(8))) short short8;
typedef __attribute__((ext_vector_type(4))) float f32x4;
typedef __attribute__((ext_vector_type(2))) float f32x2;

#define BATCH 32
#define CIN   96
#define LSEQ  4096
#define DIN   256
#define NST   16
#define MROWS (BATCH * LSEQ)   // 131072

__device__ __forceinline__ float b2f(u16 u) {
    union { unsigned int i; float f; } v; v.i = ((unsigned int)u) << 16; return v.f;
}
__device__ __forceinline__ u16 f2b(float f) {
    union { float f; unsigned int i; } v; v.f = f;
    unsigned int i = v.i;
    unsigned int lsb = (i >> 16) & 1u;
    return (u16)((i + 0x7fffu + lsb) >> 16);
}
__device__ __forceinline__ float ldv(const u16* p)   { return b2f(*p); }
__device__ __forceinline__ float ldv(const float* p) { return *p; }
__device__ __forceinline__ void stv(u16* p, float v)   { *p = f2b(v); }
__device__ __forceinline__ void stv(float* p, float v) { *p = v; }

__device__ __forceinline__ void ld8(const u16* p, float* f) {
    short8 v = *(const short8*)p;
    #pragma unroll
    for (int e = 0; e < 8; e++) f[e] = b2f((u16)v[e]);
}
__device__ __forceinline__ void ld8(const float* p, float* f) {
    f32x4 a = *(const f32x4*)p; f32x4 b = *(const f32x4*)(p + 4);
    f[0]=a[0]; f[1]=a[1]; f[2]=a[2]; f[3]=a[3];
    f[4]=b[0]; f[5]=b[1]; f[6]=b[2]; f[7]=b[3];
}

// ---------------------------------------------------------------------------
// K0: fp32 -> bf16 conversion for MFMA weight operands
// ---------------------------------------------------------------------------
__global__ __launch_bounds__(256) void k0_cvt(
    const float* __restrict__ src, u16* __restrict__ dst, int n)
{
    int i = blockIdx.x * 256 + threadIdx.x;
    if (i < n) dst[i] = f2b(src[i]);
}

// ---------------------------------------------------------------------------
// K1: xz[m, 0:512] = h_in[m, 0:96] @ in_proj_w^T + b ; h_in[b*L+l, c] = x[b,c,l]
// A staged as [l][c] (pitch 104 u16 = 208B, 16B aligned) -> ds_read_b128 frags.
// ---------------------------------------------------------------------------
__global__ __launch_bounds__(256) void k1_inproj(
    const float* __restrict__ x, const u16* __restrict__ wp,
    const float* __restrict__ bias, u16* __restrict__ xz)
{
    __shared__ u16 AtT[64 * 104];
    int m0 = blockIdx.x * 64;
    int b  = m0 >> 12;
    int l0 = m0 & 4095;
    int n0 = blockIdx.y * 256;
    int t  = threadIdx.x;
    {
        int i = t & 63, c0 = t >> 6;
        for (int c = c0; c < 96; c += 4)
            AtT[i * 104 + c] = f2b(x[((size_t)(b * 96 + c)) * 4096 + l0 + i]);
    }
    __syncthreads();
    int lane = t & 63, wid = t >> 6, q = lane >> 4, ml = lane & 15;
    f32x4 acc[16];
    #pragma unroll
    for (int f = 0; f < 16; f++)
        #pragma unroll
        for (int r = 0; r < 4; r++) acc[f][r] = 0.f;
    int arow = wid * 16 + ml;
    for (int k0 = 0; k0 < 96; k0 += 32) {
        int kb = k0 + q * 8;
        short8 a = *(const short8*)&AtT[arow * 104 + kb];
        #pragma unroll
        for (int f = 0; f < 16; f++) {
            int n = n0 + f * 16 + ml;
            short8 bf = *(const short8*)&wp[(size_t)n * 96 + kb];
            acc[f] = __builtin_amdgcn_mfma_f32_16x16x32_bf16(a, bf, acc[f], 0, 0, 0);
        }
    }
    #pragma unroll
    for (int f = 0; f < 16; f++) {
        int n = n0 + f * 16 + ml;
        float bs = bias[n];
        #pragma unroll
        for (int r = 0; r < 4; r++) {
            int m = m0 + wid * 16 + q * 4 + r;
            xz[(size_t)m * 512 + n] = f2b(acc[f][r] + bs);
        }
    }
}

// ---------------------------------------------------------------------------
// K2: u[b,l,d] = silu(depthwise causal conv k=4 over x_res) ; x_res = xz[:,0:256]
// ---------------------------------------------------------------------------
__global__ __launch_bounds__(256) void k2_conv(
    const u16* __restrict__ xz, const float* __restrict__ cw,
    const float* __restrict__ cb, u16* __restrict__ u)
{
    int d  = threadIdx.x;
    int b  = blockIdx.y;
    int l0 = blockIdx.x * 64;
    float w0 = cw[d * 4 + 0], w1 = cw[d * 4 + 1];
    float w2 = cw[d * 4 + 2], w3 = cw[d * 4 + 3];
    float bias = cb[d];
    size_t rowbase = ((size_t)b * 4096) * 512 + d;
    size_t ubase   = ((size_t)b * 4096) * 256 + d;
    float x0 = (l0 >= 3) ? b2f(xz[rowbase + (size_t)(l0 - 3) * 512]) : 0.f;
    float x1 = (l0 >= 2) ? b2f(xz[rowbase + (size_t)(l0 - 2) * 512]) : 0.f;
    float x2 = (l0 >= 1) ? b2f(xz[rowbase + (size_t)(l0 - 1) * 512]) : 0.f;
    for (int l = l0; l < l0 + 64; l++) {
        float x3 = b2f(xz[rowbase + (size_t)l * 512]);
        float s  = w0 * x0 + w1 * x1 + w2 * x2 + w3 * x3 + bias;
        float sig = 1.f / (1.f + __expf(-s));
        u[ubase + (size_t)l * 256] = f2b(s * sig);
        x0 = x1; x1 = x2; x2 = x3;
    }
}

// ---------------------------------------------------------------------------
// K3: dtbc = u_tile @ x_proj_w^T ; B,C fp32 out ; dt = softplus(dt_raw @ dt_proj_w^T + b)
// ---------------------------------------------------------------------------
template<typename DT>
__global__ __launch_bounds__(256) void k3_xproj(
    const u16* __restrict__ u, const u16* __restrict__ xw,
    const float* __restrict__ dw, const float* __restrict__ db,
    DT* __restrict__ dt, float* __restrict__ Bb, float* __restrict__ Cb)
{
    __shared__ float dtbc[64][49];
    int m0 = blockIdx.x * 64;
    int t  = threadIdx.x;
    int lane = t & 63, wid = t >> 6, q = lane >> 4, ml = lane & 15;
    f32x4 acc[3];
    #pragma unroll
    for (int f = 0; f < 3; f++)
        #pragma unroll
        for (int r = 0; r < 4; r++) acc[f][r] = 0.f;
    int arow = wid * 16 + ml;
    const u16* ap = &u[(size_t)(m0 + arow) * 256];
    #pragma unroll
    for (int k0 = 0; k0 < 256; k0 += 32) {
        short8 a = *(const short8*)&ap[k0 + q * 8];
        #pragma unroll
        for (int f = 0; f < 3; f++) {
            short8 bf = *(const short8*)&xw[(size_t)(f * 16 + ml) * 256 + k0 + q * 8];
            acc[f] = __builtin_amdgcn_mfma_f32_16x16x32_bf16(a, bf, acc[f], 0, 0, 0);
        }
    }
    #pragma unroll
    for (int f = 0; f < 3; f++)
        #pragma unroll
        for (int r = 0; r < 4; r++)
            dtbc[wid * 16 + q * 4 + r][f * 16 + ml] = acc[f][r];
    __syncthreads();
    {   // B, C writes
        int row = t >> 5, cc = t & 31;
        for (int p = 0; p < 8; p++) {
            int rr = row + p * 8;
            float v = dtbc[rr][16 + cc];
            size_t idx = (size_t)(m0 + rr) * 16 + (cc & 15);
            if (cc < 16) Bb[idx] = v; else Cb[idx] = v;
        }
    }
    {   // dt: thread = d
        int d = t;
        float wr[16];
        #pragma unroll
        for (int j = 0; j < 16; j++) wr[j] = dw[d * 16 + j];
        float bias = db[d];
        for (int r = 0; r < 64; r++) {
            float s = bias;
            #pragma unroll
            for (int j = 0; j < 16; j++) s += dtbc[r][j] * wr[j];
            float sp = (s > 20.f) ? s : __logf(1.f + __expf(s));
            stv(&dt[(size_t)(m0 + r) * 256 + d], sp);
        }
    }
}

// ---------------------------------------------------------------------------
// K4: scan pass A — per chunk: local final state (h from 0) + sum of dt.
// Fast path when A[n] == -(n+1): dA[n] = e1^(n+1), packed f32x2 math.
// ---------------------------------------------------------------------------
template<typename DT>
__global__ __launch_bounds__(256) void k4_scanA(
    const DT* __restrict__ dt, const u16* __restrict__ u,
    const float* __restrict__ Bb, const float* __restrict__ alog,
    float* __restrict__ hloc, float* __restrict__ sdt, int lchunk)
{
    __shared__ float Bs[128 * 16];
    int s = blockIdx.x, b = blockIdx.y;
    int l0 = s * lchunk;
    int d = threadIdx.x;
    float Af[16];
    bool structured = true;
    #pragma unroll
    for (int n = 0; n < 16; n++) {
        Af[n] = -__expf(alog[d * 16 + n]);
        structured = structured && (fabsf(Af[n] + (float)(n + 1)) <= 1e-3f * (n + 1));
    }
    const float* bsrc = &Bb[((size_t)b * 4096 + l0) * 16];
    for (int jj = threadIdx.x; jj < lchunk * 16; jj += 256) Bs[jj] = bsrc[jj];
    __syncthreads();
    size_t base = ((size_t)b * 4096 + l0) * 256 + d;
    size_t o = (((size_t)s * 32 + b) * 256 + d) * 16;
    float sd = 0.f;
    if (structured) {
        f32x2 h2[8];
        #pragma unroll
        for (int k = 0; k < 8; k++) h2[k] = (f32x2){0.f, 0.f};
        for (int i = 0; i < lchunk; i++) {
            float dtv = ldv(&dt[base + (size_t)i * 256]);
            float uv  = b2f(u[base + (size_t)i * 256]);
            sd += dtv;
            float du = dtv * uv;
            float e1 = __expf(-dtv);
            float e1s = e1 * e1;
            f32x2 e2 = (f32x2){e1s, e1s};
            f32x2 p  = (f32x2){e1, e1s};
            f32x2 du2 = (f32x2){du, du};
            const f32x2* B2 = (const f32x2*)&Bs[i * 16];
            #pragma unroll
            for (int k = 0; k < 8; k++) {
                h2[k] = p * h2[k] + du2 * B2[k];
                p = p * e2;
            }
        }
        #pragma unroll
        for (int k = 0; k < 8; k++) *(f32x2*)&hloc[o + 2 * k] = h2[k];
    } else {
        float h[16];
        #pragma unroll
        for (int n = 0; n < 16; n++) h[n] = 0.f;
        for (int i = 0; i < lchunk; i++) {
            float dtv = ldv(&dt[base + (size_t)i * 256]);
            float uv  = b2f(u[base + (size_t)i * 256]);
            sd += dtv;
            float du = dtv * uv;
            #pragma unroll
            for (int n = 0; n < 16; n++) {
                float dA = __expf(dtv * Af[n]);
                h[n] = dA * h[n] + du * Bs[i * 16 + n];
            }
        }
        #pragma unroll
        for (int n = 0; n < 16; n++) hloc[o + n] = h[n];
    }
    sdt[((size_t)s * 32 + b) * 256 + d] = sd;
}

// ---------------------------------------------------------------------------
// K5: carry combine across chunks per (b,d,n). Decay = exp(A[n] * sum_dt).
// ---------------------------------------------------------------------------
__global__ __launch_bounds__(256) void k5_scanB(
    const float* __restrict__ hloc, const float* __restrict__ sdt,
    const float* __restrict__ alog, float* __restrict__ hin, int nch)
{
    int t = blockIdx.x * 256 + threadIdx.x;   // (b, d, n)
    int b = t >> 12;
    int rem = t & 4095;                        // d*16 + n
    int d = rem >> 4;
    float A = -__expf(alog[rem]);
    float h = 0.f;
    for (int s = 0; s < nch; s++) {
        size_t o = ((size_t)(s * 32 + b)) * 4096 + rem;
        float hl = hloc[o];
        float sd = sdt[((size_t)(s * 32 + b)) * 256 + d];
        hin[o] = h;
        h = __expf(A * sd) * h + hl;
    }
}

// ---------------------------------------------------------------------------
// K6: scan pass C — true scan with carry-in; fuse y+u*D, *silu(z), +x_res.
// Writes pre-LN1 tensor t (TT = u16 in-place over u, or fp32 region).
// ---------------------------------------------------------------------------
template<typename DT, typename TT>
__global__ __launch_bounds__(256) void k6_scanC(
    const DT* __restrict__ dt, const u16* __restrict__ u,
    const float* __restrict__ Bb, const float* __restrict__ Cb,
    const float* __restrict__ alog, const float* __restrict__ hin,
    const u16* __restrict__ xz, const float* __restrict__ Dp,
    TT* __restrict__ tp, int lchunk)
{
    __shared__ float Bs[128 * 16];
    __shared__ float Cs[128 * 16];
    int s = blockIdx.x, b = blockIdx.y;
    int l0 = s * lchunk;
    int d = threadIdx.x;
    float Af[16];
    bool structured = true;
    #pragma unroll
    for (int n = 0; n < 16; n++) {
        Af[n] = -__expf(alog[d * 16 + n]);
        structured = structured && (fabsf(Af[n] + (float)(n + 1)) <= 1e-3f * (n + 1));
    }
    {
        const float* bsrc = &Bb[((size_t)b * 4096 + l0) * 16];
        const float* csrc = &Cb[((size_t)b * 4096 + l0) * 16];
        for (int jj = threadIdx.x; jj < lchunk * 16; jj += 256) {
            Bs[jj] = bsrc[jj]; Cs[jj] = csrc[jj];
        }
    }
    __syncthreads();
    size_t o = (((size_t)s * 32 + b) * 256 + d) * 16;
    float Dv = Dp[d];
    size_t base  = ((size_t)b * 4096 + l0) * 256 + d;
    size_t zbase = ((size_t)b * 4096 + l0) * 512 + d;
    if (structured) {
        f32x2 h2[8];
        #pragma unroll
        for (int k = 0; k < 8; k++) h2[k] = *(const f32x2*)&hin[o + 2 * k];
        for (int i = 0; i < lchunk; i++) {
            float dtv = ldv(&dt[base + (size_t)i * 256]);
            float uv  = b2f(u[base + (size_t)i * 256]);
            float du = dtv * uv;
            float e1 = __expf(-dtv);
            float e1s = e1 * e1;
            f32x2 e2 = (f32x2){e1s, e1s};
            f32x2 p  = (f32x2){e1, e1s};
            f32x2 du2 = (f32x2){du, du};
            f32x2 y2 = (f32x2){0.f, 0.f};
            const f32x2* B2 = (const f32x2*)&Bs[i * 16];
            const f32x2* C2 = (const f32x2*)&Cs[i * 16];
            #pragma unroll
            for (int k = 0; k < 8; k++) {
                h2[k] = p * h2[k] + du2 * B2[k];
                y2 = y2 + h2[k] * C2[k];
                p = p * e2;
            }
            float y = y2[0] + y2[1] + uv * Dv;
            float zv = b2f(xz[zbase + (size_t)i * 512 + 256]);
            float xr = b2f(xz[zbase + (size_t)i * 512]);
            float sig = 1.f / (1.f + __expf(-zv));
            y *= zv * sig;
            stv(&tp[base + (size_t)i * 256], y + xr);
        }
    } else {
        float h[16];
        #pragma unroll
        for (int n = 0; n < 16; n++) h[n] = hin[o + n];
        for (int i = 0; i < lchunk; i++) {
            float dtv = ldv(&dt[base + (size_t)i * 256]);
            float uv  = b2f(u[base + (size_t)i * 256]);
            float du = dtv * uv;
            float y = 0.f;
            #pragma unroll
            for (int n = 0; n < 16; n++) {
                float dA = __expf(dtv * Af[n]);
                h[n] = dA * h[n] + du * Bs[i * 16 + n];
                y += h[n] * Cs[i * 16 + n];
            }
            y += uv * Dv;
            float zv = b2f(xz[zbase + (size_t)i * 512 + 256]);
            float xr = b2f(xz[zbase + (size_t)i * 512]);
            float sig = 1.f / (1.f + __expf(-zv));
            y *= zv * sig;
            stv(&tp[base + (size_t)i * 256], y + xr);
        }
    }
}

// ---------------------------------------------------------------------------
// K8: y1 = LN1(t); y_proj = y1 @ out_proj_w^T + ob; out = LN2(y1 + y_proj)
// LN1 is two-pass from source so fp32 t isn't quantized before mean/var.
// ---------------------------------------------------------------------------
template<typename TT>
__global__ __launch_bounds__(256) void k8_final(
    const TT* __restrict__ tb, const u16* __restrict__ ow,
    const float* __restrict__ ob, const float* __restrict__ g1,
    const float* __restrict__ bb1, const float* __restrict__ g2,
    const float* __restrict__ bb2, float* __restrict__ out)
{
    __shared__ u16 Yt[64 * 272];
    int m0 = blockIdx.x * 64;
    int t  = threadIdx.x;
    {   // LN1 (4 threads per row, shuffle-combine partials)
        int r = t >> 2, ccol = (t & 3) * 64;
        const TT* src = &tb[(size_t)(m0 + r) * 256 + ccol];
        u16* dst = &Yt[r * 272 + ccol];
        float sum = 0.f, sq = 0.f;
        for (int jj = 0; jj < 64; jj += 8) {
            float f[8]; ld8(src + jj, f);
            #pragma unroll
            for (int e = 0; e < 8; e++) { sum += f[e]; sq += f[e] * f[e]; }
        }
        sum += __shfl_xor(sum, 1); sq += __shfl_xor(sq, 1);
        sum += __shfl_xor(sum, 2); sq += __shfl_xor(sq, 2);
        float mean = sum * (1.f / 256.f);
        float var  = sq * (1.f / 256.f) - mean * mean;
        float rstd = rsqrtf(var + 1e-5f);
        for (int jj = 0; jj < 64; jj += 8) {
            float f[8]; ld8(src + jj, f);
            #pragma unroll
            for (int e = 0; e < 8; e++) {
                int c = ccol + jj + e;
                dst[jj + e] = f2b((f[e] - mean) * rstd * g1[c] + bb1[c]);
            }
        }
    }
    __syncthreads();
    int lane = t & 63, wid = t >> 6, q = lane >> 4, ml = lane & 15;
    f32x4 acc[16];
    #pragma unroll
    for (int f = 0; f < 16; f++)
        #pragma unroll
        for (int r = 0; r < 4; r++) acc[f][r] = 0.f;
    int arow = wid * 16 + ml;
    #pragma unroll
    for (int k0 = 0; k0 < 256; k0 += 32) {
        short8 a = *(const short8*)&Yt[arow * 272 + k0 + q * 8];
        #pragma unroll
        for (int f = 0; f < 16; f++) {
            short8 bf = *(const short8*)&ow[(size_t)(f * 16 + ml) * 256 + k0 + q * 8];
            acc[f] = __builtin_amdgcn_mfma_f32_16x16x32_bf16(a, bf, acc[f], 0, 0, 0);
        }
    }
    float ps[4] = {0, 0, 0, 0}, psq[4] = {0, 0, 0, 0};
    #pragma unroll
    for (int f = 0; f < 16; f++) {
        int col = f * 16 + ml;
        float obv = ob[col];
        #pragma unroll
        for (int r = 0; r < 4; r++) {
            int row = wid * 16 + q * 4 + r;
            float v = acc[f][r] + obv + b2f(Yt[row * 272 + col]);
            acc[f][r] = v;
            ps[r] += v; psq[r] += v * v;
        }
    }
    #pragma unroll
    for (int msk = 1; msk < 16; msk <<= 1) {
        #pragma unroll
        for (int r = 0; r < 4; r++) {
            ps[r]  += __shfl_xor(ps[r],  msk);
            psq[r] += __shfl_xor(psq[r], msk);
        }
    }
    #pragma unroll
    for (int f = 0; f < 16; f++) {
        int col = f * 16 + ml;
        float g2v = g2[col], b2v = bb2[col];
        #pragma unroll
        for (int r = 0; r < 4; r++) {
            int row = wid * 16 + q * 4 + r;
            float mean = ps[r] * (1.f / 256.f);
            float var  = psq[r] * (1.f / 256.f) - mean * mean;
            float rstd = rsqrtf(var + 1e-5f);
            out[(size_t)(m0 + row) * 256 + col] = (acc[f][r] - mean) * rstd * g2v + b2v;
        }
    }
}

extern "C" void kernel_launch(void* const* d_in, const int* in_sizes, int n_in,
                              void* d_out, int out_size, void* d_ws, size_t ws_size,
                              hipStream_t stream)
{
    const float* x    = (const float*)d_in[0];
    const float* ipw  = (const float*)d_in[1];
    const float* ipb  = (const float*)d_in[2];
    const float* cw   = (const float*)d_in[3];
    const float* cb   = (const float*)d_in[4];
    const float* xpw  = (const float*)d_in[5];
    const float* dpw  = (const float*)d_in[6];
    const float* dpb  = (const float*)d_in[7];
    const float* opw  = (const float*)d_in[8];
    const float* opb  = (const float*)d_in[9];
    const float* alog = (const float*)d_in[10];
    const float* Dp   = (const float*)d_in[11];
    const float* g1   = (const float*)d_in[12];
    const float* b1   = (const float*)d_in[13];
    const float* g2   = (const float*)d_in[14];
    const float* b2   = (const float*)d_in[15];
    float* outp = (float*)d_out;

    char* ws = (char*)d_ws;
    // Fixed region
    u16*   xz  = (u16*)ws;                          // 134217728 B
    u16*   u   = (u16*)(ws + 134217728);            //  67108864 B
    float* Bb  = (float*)(ws + 201326592);          //   8388608 B
    float* Cb  = (float*)(ws + 209715200);          //   8388608 B
    u16* ipw_b = (u16*)(ws + 218103808);            // 49152 el
    u16* xpw_b = ipw_b + 49152;                     // 12288 el
    u16* opw_b = xpw_b + 12288;                     // 65536 el
    const size_t base = 218103808 + 262144;         // 218365952 (weights padded)

    // Tiered variable region: dt (bf16|fp32), hloc/hin/sdt (NC chunks), t (fp32 opt)
    const size_t T32B = 134217728;
    auto chunkBytes = [](size_t nc) { return nc * (524288 * 2 + 32768); };
    int NC; int DT32; int T32;
    if      (ws_size >= base + 134217728 + chunkBytes(64) + T32B) { NC = 64; DT32 = 1; T32 = 1; }
    else if (ws_size >= base + 134217728 + chunkBytes(64))        { NC = 64; DT32 = 1; T32 = 0; }
    else if (ws_size >= base +  67108864 + chunkBytes(64))        { NC = 64; DT32 = 0; T32 = 0; }
    else                                                          { NC = 32; DT32 = 0; T32 = 0; }
    size_t dtB = DT32 ? 134217728 : 67108864;
    void*  dtp  = (void*)(ws + base);
    float* hloc = (float*)(ws + base + dtB);
    float* hin  = hloc + (size_t)NC * 131072;
    float* sdt  = hin  + (size_t)NC * 131072;
    float* t32  = T32 ? (float*)(ws + base + dtB + chunkBytes((size_t)NC)) : nullptr;
    int lchunk = LSEQ / NC;

    k0_cvt<<<192, 256, 0, stream>>>(ipw, ipw_b, 49152);
    k0_cvt<<<48,  256, 0, stream>>>(xpw, xpw_b, 12288);
    k0_cvt<<<256, 256, 0, stream>>>(opw, opw_b, 65536);
    k1_inproj<<<dim3(2048, 2), 256, 0, stream>>>(x, ipw_b, ipb, xz);
    k2_conv  <<<dim3(64, 32),  256, 0, stream>>>(xz, cw, cb, u);
    if (DT32) {
        float* dt = (float*)dtp;
        k3_xproj<float><<<2048, 256, 0, stream>>>(u, xpw_b, dpw, dpb, dt, Bb, Cb);
        k4_scanA<float><<<dim3(NC, 32), 256, 0, stream>>>(dt, u, Bb, alog, hloc, sdt, lchunk);
        k5_scanB<<<512, 256, 0, stream>>>(hloc, sdt, alog, hin, NC);
        if (T32) {
            k6_scanC<float, float><<<dim3(NC, 32), 256, 0, stream>>>(dt, u, Bb, Cb, alog, hin, xz, Dp, t32, lchunk);
            k8_final<float><<<2048, 256, 0, stream>>>(t32, opw_b, opb, g1, b1, g2, b2, outp);
        } else {
            k6_scanC<float, u16><<<dim3(NC, 32), 256, 0, stream>>>(dt, u, Bb, Cb, alog, hin, xz, Dp, u, lchunk);
            k8_final<u16><<<2048, 256, 0, stream>>>(u, opw_b, opb, g1, b1, g2, b2, outp);
        }
    } else {
        u16* dt = (u16*)dtp;
        k3_xproj<u16><<<2048, 256, 0, stream>>>(u, xpw_b, dpw, dpb, dt, Bb, Cb);
        k4_scanA<u16><<<dim3(NC, 32), 256, 0, stream>>>(dt, u, Bb, alog, hloc, sdt, lchunk);
        k5_scanB<<<512, 256, 0, stream>>>(hloc, sdt, alog, hin, NC);
        k6_scanC<u16, u16><<<dim3(NC, 32), 256, 0, stream>>>(dt, u, Bb, Cb, alog, hin, xz, Dp, u, lchunk);
        k8_final<u16><<<2048, 256, 0, stream>>>(u, opw_b, opb, g1, b1, g2, b2, outp);
    }
}